// Round 1
// baseline (2546.786 us; speedup 1.0000x reference)
//
#include <hip/hip_runtime.h>
#include <hip/hip_bf16.h>

// Problem: B=4, T=2048, E=768, H=12, hd=64. All f32.
// Round 0: correct f32 baseline.
//   k1: qkv = x @ Wqkv, scattered to q/k/v in [B,H,T,hd] layout (ws)
//   k2: causal flash attention per (b,h,32-row q-block), writes [B,T,E] (ws)
//   k3: out = attn @ Wproj
// ws usage: 4 * B*T*E floats = 100.7 MB

#define BB 4
#define TT 2048
#define EE 768
#define HH 12
#define HD 64
#define NQKV 2304
#define BTE (BB*TT*EE)  // 6291456

// ---------------------------------------------------------------------------
// Tiled f32 GEMM: C[M=8192, N=2304] = x[8192,768] @ Wqkv[768,2304]
// 64x64 tile per block, 256 threads, each thread 4x4. Scatter epilogue.
// ---------------------------------------------------------------------------
__global__ __launch_bounds__(256)
void qkv_gemm_kernel(const float* __restrict__ x, const float* __restrict__ w,
                     float* __restrict__ qkv_ws) {
    __shared__ float As[64][17];
    __shared__ float Bs[16][68];
    const int bx = blockIdx.x;   // n tile: 0..35
    const int by = blockIdx.y;   // m tile: 0..127
    const int tid = threadIdx.x;
    const int tr = tid >> 4;     // 0..15
    const int tc = tid & 15;     // 0..15

    const int arow = tid >> 2;          // 0..63
    const int acol = (tid & 3) << 2;    // 0,4,8,12
    const int brow = tid >> 4;          // 0..15
    const int bcol = (tid & 15) << 2;   // 0..60

    const float* xrow = x + (size_t)(by * 64 + arow) * EE;
    const float* wcol = w + (size_t)bx * 64;

    float acc[4][4] = {};

    for (int kt = 0; kt < EE / 16; ++kt) {
        float4 a4 = *(const float4*)(xrow + kt * 16 + acol);
        float4 b4 = *(const float4*)(wcol + (size_t)(kt * 16 + brow) * NQKV + bcol);
        __syncthreads();   // previous iteration finished reading LDS
        As[arow][acol + 0] = a4.x; As[arow][acol + 1] = a4.y;
        As[arow][acol + 2] = a4.z; As[arow][acol + 3] = a4.w;
        Bs[brow][bcol + 0] = b4.x; Bs[brow][bcol + 1] = b4.y;
        Bs[brow][bcol + 2] = b4.z; Bs[brow][bcol + 3] = b4.w;
        __syncthreads();
#pragma unroll
        for (int kk = 0; kk < 16; ++kk) {
            float a[4], b[4];
#pragma unroll
            for (int i = 0; i < 4; ++i) a[i] = As[tr * 4 + i][kk];
#pragma unroll
            for (int j = 0; j < 4; ++j) b[j] = Bs[kk][tc * 4 + j];
#pragma unroll
            for (int i = 0; i < 4; ++i)
#pragma unroll
                for (int j = 0; j < 4; ++j) acc[i][j] += a[i] * b[j];
        }
    }

    // Scatter: column n -> which=n/768 (q/k/v), e=n%768, h=e/64, d=e%64.
    // Block's 64 columns lie in one (which, h).
    const int nbase = bx * 64;
    const int which = nbase / EE;
    const int h = (nbase % EE) / HD;
    float* dst = qkv_ws + (size_t)which * BTE;
#pragma unroll
    for (int i = 0; i < 4; ++i) {
        const int mrow = by * 64 + tr * 4 + i;
        const int b = mrow / TT, t = mrow % TT;
        float* drow = dst + ((size_t)(b * HH + h) * TT + t) * HD;
        *(float4*)&drow[tc * 4] = make_float4(acc[i][0], acc[i][1], acc[i][2], acc[i][3]);
    }
}

// ---------------------------------------------------------------------------
// Causal flash attention. One block = (b, h, 32 q-rows). 256 threads.
// thread t: row r = t/8, col/d group cg = t%8 (8 cols or 8 d each).
// ---------------------------------------------------------------------------
__global__ __launch_bounds__(256)
void attn_kernel(const float* __restrict__ q, const float* __restrict__ k,
                 const float* __restrict__ v, float* __restrict__ attn_out) {
    __shared__ float Qs[32][65];
    __shared__ float Ks[64][65];
    __shared__ float Vs[64][65];
    __shared__ float Ps[32][65];

    const int qi = blockIdx.x;   // 0..63
    const int h  = blockIdx.y;
    const int b  = blockIdx.z;
    const int tid = threadIdx.x;
    const int r  = tid >> 3;     // 0..31
    const int cg = tid & 7;      // 0..7

    const size_t head_off = (size_t)(b * HH + h) * TT * HD;
    const float* qp = q + head_off;
    const float* kp = k + head_off;
    const float* vp = v + head_off;

    const int qbase = qi * 32;
    const int qglob = qbase + r;

    // stage Q (32x64)
    for (int i = tid; i < 32 * 16; i += 256) {
        const int row = i >> 4, c4 = (i & 15) << 2;
        float4 q4 = *(const float4*)&qp[(size_t)(qbase + row) * HD + c4];
        Qs[row][c4 + 0] = q4.x; Qs[row][c4 + 1] = q4.y;
        Qs[row][c4 + 2] = q4.z; Qs[row][c4 + 3] = q4.w;
    }

    float m = -INFINITY, l = 0.f;
    float o[8] = {};

    const int ktiles = qi / 2 + 1;   // floor((qbase+31)/64)+1
    for (int kt = 0; kt < ktiles; ++kt) {
        const int kbase = kt * 64;
        __syncthreads();   // prev iter done reading Ks/Vs
        for (int i = tid; i < 64 * 16; i += 256) {
            const int row = i >> 4, c4 = (i & 15) << 2;
            float4 k4 = *(const float4*)&kp[(size_t)(kbase + row) * HD + c4];
            Ks[row][c4 + 0] = k4.x; Ks[row][c4 + 1] = k4.y;
            Ks[row][c4 + 2] = k4.z; Ks[row][c4 + 3] = k4.w;
            float4 v4 = *(const float4*)&vp[(size_t)(kbase + row) * HD + c4];
            Vs[row][c4 + 0] = v4.x; Vs[row][c4 + 1] = v4.y;
            Vs[row][c4 + 2] = v4.z; Vs[row][c4 + 3] = v4.w;
        }
        __syncthreads();

        // S = Q K^T / 8 for this thread's 8 columns
        float s[8] = {};
#pragma unroll 8
        for (int kk = 0; kk < 64; ++kk) {
            const float qv = Qs[r][kk];
#pragma unroll
            for (int cc = 0; cc < 8; ++cc) s[cc] += qv * Ks[cg * 8 + cc][kk];
        }
        float mx = -INFINITY;
#pragma unroll
        for (int cc = 0; cc < 8; ++cc) {
            const int kg = kbase + cg * 8 + cc;
            s[cc] = (kg > qglob) ? -INFINITY : s[cc] * 0.125f;
            mx = fmaxf(mx, s[cc]);
        }
        // row max across the 8 threads of this row
        mx = fmaxf(mx, __shfl_xor(mx, 1));
        mx = fmaxf(mx, __shfl_xor(mx, 2));
        mx = fmaxf(mx, __shfl_xor(mx, 4));

        const float mnew = fmaxf(m, mx);
        const float alpha = __expf(m - mnew);
        float psum = 0.f;
#pragma unroll
        for (int cc = 0; cc < 8; ++cc) {
            const float p = __expf(s[cc] - mnew);
            Ps[r][cg * 8 + cc] = p;
            psum += p;
        }
        psum += __shfl_xor(psum, 1);
        psum += __shfl_xor(psum, 2);
        psum += __shfl_xor(psum, 4);
        l = l * alpha + psum;
        m = mnew;
#pragma unroll
        for (int dd = 0; dd < 8; ++dd) o[dd] *= alpha;

        // P (row r) written and read by the same 8 lanes of one wave: no
        // cross-wave hazard; compiler orders LDS within a wave.
#pragma unroll 4
        for (int c = 0; c < 64; ++c) {
            const float pv = Ps[r][c];
#pragma unroll
            for (int dd = 0; dd < 8; ++dd) o[dd] += pv * Vs[c][cg * 8 + dd];
        }
    }

    const float inv_l = 1.f / l;
    float* orow = attn_out + ((size_t)(b * TT) + qglob) * EE + h * HD + cg * 8;
#pragma unroll
    for (int dd = 0; dd < 8; ++dd) orow[dd] = o[dd] * inv_l;
}

// ---------------------------------------------------------------------------
// Proj GEMM: out[8192,768] = attn[8192,768] @ Wproj[768,768]
// ---------------------------------------------------------------------------
__global__ __launch_bounds__(256)
void proj_gemm_kernel(const float* __restrict__ a, const float* __restrict__ w,
                      float* __restrict__ out) {
    __shared__ float As[64][17];
    __shared__ float Bs[16][68];
    const int bx = blockIdx.x;   // 0..11
    const int by = blockIdx.y;   // 0..127
    const int tid = threadIdx.x;
    const int tr = tid >> 4;
    const int tc = tid & 15;

    const int arow = tid >> 2;
    const int acol = (tid & 3) << 2;
    const int brow = tid >> 4;
    const int bcol = (tid & 15) << 2;

    const float* arow_p = a + (size_t)(by * 64 + arow) * EE;
    const float* wcol_p = w + (size_t)bx * 64;

    float acc[4][4] = {};

    for (int kt = 0; kt < EE / 16; ++kt) {
        float4 a4 = *(const float4*)(arow_p + kt * 16 + acol);
        float4 b4 = *(const float4*)(wcol_p + (size_t)(kt * 16 + brow) * EE + bcol);
        __syncthreads();
        As[arow][acol + 0] = a4.x; As[arow][acol + 1] = a4.y;
        As[arow][acol + 2] = a4.z; As[arow][acol + 3] = a4.w;
        Bs[brow][bcol + 0] = b4.x; Bs[brow][bcol + 1] = b4.y;
        Bs[brow][bcol + 2] = b4.z; Bs[brow][bcol + 3] = b4.w;
        __syncthreads();
#pragma unroll
        for (int kk = 0; kk < 16; ++kk) {
            float a_[4], b_[4];
#pragma unroll
            for (int i = 0; i < 4; ++i) a_[i] = As[tr * 4 + i][kk];
#pragma unroll
            for (int j = 0; j < 4; ++j) b_[j] = Bs[kk][tc * 4 + j];
#pragma unroll
            for (int i = 0; i < 4; ++i)
#pragma unroll
                for (int j = 0; j < 4; ++j) acc[i][j] += a_[i] * b_[j];
        }
    }

#pragma unroll
    for (int i = 0; i < 4; ++i) {
        const int mrow = by * 64 + tr * 4 + i;
        *(float4*)&out[(size_t)mrow * EE + bx * 64 + tc * 4] =
            make_float4(acc[i][0], acc[i][1], acc[i][2], acc[i][3]);
    }
}

extern "C" void kernel_launch(void* const* d_in, const int* in_sizes, int n_in,
                              void* d_out, int out_size, void* d_ws, size_t ws_size,
                              hipStream_t stream) {
    const float* x     = (const float*)d_in[0];
    const float* wqkv  = (const float*)d_in[1];
    const float* wproj = (const float*)d_in[2];
    float* out = (float*)d_out;
    float* ws  = (float*)d_ws;

    float* q_ws    = ws;                      // [B,H,T,hd]
    float* k_ws    = ws + (size_t)BTE;
    float* v_ws    = ws + 2 * (size_t)BTE;
    float* attn_ws = ws + 3 * (size_t)BTE;    // [B,T,E]

    qkv_gemm_kernel<<<dim3(NQKV / 64, (BB * TT) / 64), 256, 0, stream>>>(x, wqkv, ws);
    attn_kernel<<<dim3(TT / 32, HH, BB), 256, 0, stream>>>(q_ws, k_ws, v_ws, attn_ws);
    proj_gemm_kernel<<<dim3(EE / 64, (BB * TT) / 64), 256, 0, stream>>>(attn_ws, wproj, out);
}

// Round 2
// 766.431 us; speedup vs baseline: 3.3229x; 3.3229x over previous
//
#include <hip/hip_runtime.h>
#include <hip/hip_bf16.h>

// B=4, T=2048, E=768, H=12, hd=64.
// Round 1: bf16 MFMA flash attention.
//   k1: qkv = x @ Wqkv (f32 compute), emits bf16 q,k [B,H,T,64] and v^T [B,H,64,T]
//   k2: MFMA flash attention (16x16x32 bf16), writes f32 [B,T,E]
//   k3: proj GEMM f32 (unchanged)

#define BB 4
#define TT 2048
#define EE 768
#define HH 12
#define HD 64
#define NQKV 2304
#define BTE (BB*TT*EE)  // 6291456

typedef __attribute__((ext_vector_type(8))) short bf16x8;
typedef __attribute__((ext_vector_type(4))) float f32x4;

static __device__ __forceinline__ unsigned short f2bf(float f) {
    unsigned u = __builtin_bit_cast(unsigned, f);
    u += 0x7fffu + ((u >> 16) & 1u);   // RNE
    return (unsigned short)(u >> 16);
}

// ---------------------------------------------------------------------------
// QKV GEMM: [8192,768] @ [768,2304], f32 compute, bf16 scattered outputs.
// ---------------------------------------------------------------------------
__global__ __launch_bounds__(256)
void qkv_gemm_kernel(const float* __restrict__ x, const float* __restrict__ w,
                     unsigned short* __restrict__ q_ws,
                     unsigned short* __restrict__ k_ws,
                     unsigned short* __restrict__ v_ws) {
    __shared__ float As[64][17];
    __shared__ float Bs[16][68];
    const int bx = blockIdx.x;   // n tile: 0..35
    const int by = blockIdx.y;   // m tile: 0..127
    const int tid = threadIdx.x;
    const int tr = tid >> 4;
    const int tc = tid & 15;

    const int arow = tid >> 2;
    const int acol = (tid & 3) << 2;
    const int brow = tid >> 4;
    const int bcol = (tid & 15) << 2;

    const float* xrow = x + (size_t)(by * 64 + arow) * EE;
    const float* wcol = w + (size_t)bx * 64;

    float acc[4][4] = {};

    for (int kt = 0; kt < EE / 16; ++kt) {
        float4 a4 = *(const float4*)(xrow + kt * 16 + acol);
        float4 b4 = *(const float4*)(wcol + (size_t)(kt * 16 + brow) * NQKV + bcol);
        __syncthreads();
        As[arow][acol + 0] = a4.x; As[arow][acol + 1] = a4.y;
        As[arow][acol + 2] = a4.z; As[arow][acol + 3] = a4.w;
        Bs[brow][bcol + 0] = b4.x; Bs[brow][bcol + 1] = b4.y;
        Bs[brow][bcol + 2] = b4.z; Bs[brow][bcol + 3] = b4.w;
        __syncthreads();
#pragma unroll
        for (int kk = 0; kk < 16; ++kk) {
            float a[4], b[4];
#pragma unroll
            for (int i = 0; i < 4; ++i) a[i] = As[tr * 4 + i][kk];
#pragma unroll
            for (int j = 0; j < 4; ++j) b[j] = Bs[kk][tc * 4 + j];
#pragma unroll
            for (int i = 0; i < 4; ++i)
#pragma unroll
                for (int j = 0; j < 4; ++j) acc[i][j] += a[i] * b[j];
        }
    }

    const int nbase = bx * 64;
    const int which = nbase / EE;          // 0=q 1=k 2=v
    const int h = (nbase % EE) / HD;
    const int mbase = by * 64 + tr * 4;
    const int b = mbase / TT;
    const int tbase = mbase % TT;          // 4 consecutive t rows

    if (which == 2) {
        // V transposed: v_ws[((b*H + h)*64 + d)*T + t], pack 4 t per store
#pragma unroll
        for (int j = 0; j < 4; ++j) {
            const int d = tc * 4 + j;
            ushort4 pk;
            pk.x = f2bf(acc[0][j]); pk.y = f2bf(acc[1][j]);
            pk.z = f2bf(acc[2][j]); pk.w = f2bf(acc[3][j]);
            *(ushort4*)&v_ws[(((size_t)b * HH + h) * HD + d) * TT + tbase] = pk;
        }
    } else {
        unsigned short* dst = (which == 0) ? q_ws : k_ws;
#pragma unroll
        for (int i = 0; i < 4; ++i) {
            ushort4 pk;
            pk.x = f2bf(acc[i][0]); pk.y = f2bf(acc[i][1]);
            pk.z = f2bf(acc[i][2]); pk.w = f2bf(acc[i][3]);
            *(ushort4*)&dst[(((size_t)b * HH + h) * TT + tbase + i) * HD + tc * 4] = pk;
        }
    }
}

// ---------------------------------------------------------------------------
// MFMA flash attention. Block = (b, h, 64 q rows), 256 threads = 4 waves,
// wave w owns q rows [q0, q0+16). KV tiles of 64 staged in padded LDS.
// ---------------------------------------------------------------------------
__global__ __launch_bounds__(256)
void attn_kernel(const unsigned short* __restrict__ q,
                 const unsigned short* __restrict__ k,
                 const unsigned short* __restrict__ vt,
                 float* __restrict__ attn_out) {
    __shared__ __align__(16) unsigned short Ks[64 * 72];   // [key][d], pad 8
    __shared__ __align__(16) unsigned short Vt[64 * 72];   // [d][key], pad 8
    __shared__ __align__(16) unsigned short Pb[4 * 16 * 72];

    const int qi = (TT / 64 - 1) - blockIdx.x;   // heavy blocks first
    const int h = blockIdx.y, b = blockIdx.z;
    const int tid = threadIdx.x;
    const int w = tid >> 6;
    const int lane = tid & 63;
    const int c = lane & 15;
    const int g = lane >> 4;

    const size_t head_off = (size_t)(b * HH + h) * TT * HD;
    const unsigned short* qp = q + head_off;
    const unsigned short* kp = k + head_off;
    const unsigned short* vp = vt + head_off;   // rows d, length T

    const int q0 = qi * 64 + w * 16;

    // Q A-fragments (row = c, k-slots over d)
    const bf16x8 qa0 = *(const bf16x8*)&qp[(size_t)(q0 + c) * HD + g * 8];
    const bf16x8 qa1 = *(const bf16x8*)&qp[(size_t)(q0 + c) * HD + 32 + g * 8];

    f32x4 o[4] = {};                 // [d-block] x 4 q rows
    float m_r[4], l_r[4];
#pragma unroll
    for (int r = 0; r < 4; ++r) { m_r[r] = -INFINITY; l_r[r] = 0.f; }

    const int skey = tid >> 2;       // staging row 0..63
    const int sc = tid & 3;          // staging chunk

    const int ktiles = qi + 1;
    for (int kt = 0; kt < ktiles; ++kt) {
        const int kv0 = kt * 64;
        // issue global loads before the barrier
        const uint4 kA = *(const uint4*)&kp[(size_t)(kv0 + skey) * HD + sc * 16];
        const uint4 kB = *(const uint4*)&kp[(size_t)(kv0 + skey) * HD + sc * 16 + 8];
        const uint4 vA = *(const uint4*)&vp[(size_t)skey * TT + kv0 + sc * 16];
        const uint4 vB = *(const uint4*)&vp[(size_t)skey * TT + kv0 + sc * 16 + 8];
        __syncthreads();   // previous tile's LDS reads done
        *(uint4*)&Ks[skey * 72 + sc * 16]     = kA;
        *(uint4*)&Ks[skey * 72 + sc * 16 + 8] = kB;
        *(uint4*)&Vt[skey * 72 + sc * 16]     = vA;
        *(uint4*)&Vt[skey * 72 + sc * 16 + 8] = vB;
        __syncthreads();

        // ---- QK^T: S[16 q][64 key] per wave ----
        f32x4 s[4];
#pragma unroll
        for (int kb = 0; kb < 4; ++kb) {
            const bf16x8 kb0 = *(const bf16x8*)&Ks[(kb * 16 + c) * 72 + g * 8];
            const bf16x8 kb1 = *(const bf16x8*)&Ks[(kb * 16 + c) * 72 + 32 + g * 8];
            f32x4 z = {0.f, 0.f, 0.f, 0.f};
            z = __builtin_amdgcn_mfma_f32_16x16x32_bf16(qa0, kb0, z, 0, 0, 0);
            s[kb] = __builtin_amdgcn_mfma_f32_16x16x32_bf16(qa1, kb1, z, 0, 0, 0);
        }

        // ---- online softmax (D layout: row q = 4g+r, col key = kb*16+c) ----
        float mx[4] = {-INFINITY, -INFINITY, -INFINITY, -INFINITY};
        if (kt == qi) {
#pragma unroll
            for (int kb = 0; kb < 4; ++kb)
#pragma unroll
                for (int r = 0; r < 4; ++r) {
                    const bool masked = (kv0 + kb * 16 + c) > (q0 + 4 * g + r);
                    s[kb][r] = masked ? -INFINITY : s[kb][r] * 0.125f;
                }
        } else {
#pragma unroll
            for (int kb = 0; kb < 4; ++kb)
#pragma unroll
                for (int r = 0; r < 4; ++r) s[kb][r] *= 0.125f;
        }
#pragma unroll
        for (int kb = 0; kb < 4; ++kb)
#pragma unroll
            for (int r = 0; r < 4; ++r) mx[r] = fmaxf(mx[r], s[kb][r]);
#pragma unroll
        for (int d = 1; d < 16; d <<= 1)
#pragma unroll
            for (int r = 0; r < 4; ++r) mx[r] = fmaxf(mx[r], __shfl_xor(mx[r], d));

        float al[4], ps[4];
#pragma unroll
        for (int r = 0; r < 4; ++r) {
            const float mn = fmaxf(m_r[r], mx[r]);
            al[r] = __expf(m_r[r] - mn);
            m_r[r] = mn;
            ps[r] = 0.f;
        }
#pragma unroll
        for (int kb = 0; kb < 4; ++kb)
#pragma unroll
            for (int r = 0; r < 4; ++r) {
                const float pv = __expf(s[kb][r] - m_r[r]);
                ps[r] += pv;
                Pb[w * 16 * 72 + (4 * g + r) * 72 + kb * 16 + c] = f2bf(pv);
            }
#pragma unroll
        for (int d = 1; d < 16; d <<= 1)
#pragma unroll
            for (int r = 0; r < 4; ++r) ps[r] += __shfl_xor(ps[r], d);
#pragma unroll
        for (int r = 0; r < 4; ++r) l_r[r] = l_r[r] * al[r] + ps[r];
#pragma unroll
        for (int db = 0; db < 4; ++db)
#pragma unroll
            for (int r = 0; r < 4; ++r) o[db][r] *= al[r];

        // ---- PV: O[16 q][64 d] += P[16x64] V[64x64] ----
        // Pb is wave-private; within-wave LDS dependency handled by compiler.
        const bf16x8 pa0 = *(const bf16x8*)&Pb[w * 16 * 72 + c * 72 + g * 8];
        const bf16x8 pa1 = *(const bf16x8*)&Pb[w * 16 * 72 + c * 72 + 32 + g * 8];
#pragma unroll
        for (int db = 0; db < 4; ++db) {
            const bf16x8 vb0 = *(const bf16x8*)&Vt[(db * 16 + c) * 72 + g * 8];
            const bf16x8 vb1 = *(const bf16x8*)&Vt[(db * 16 + c) * 72 + 32 + g * 8];
            o[db] = __builtin_amdgcn_mfma_f32_16x16x32_bf16(pa0, vb0, o[db], 0, 0, 0);
            o[db] = __builtin_amdgcn_mfma_f32_16x16x32_bf16(pa1, vb1, o[db], 0, 0, 0);
        }
    }

    float invl[4];
#pragma unroll
    for (int r = 0; r < 4; ++r) invl[r] = 1.f / l_r[r];
    float* op = attn_out + ((size_t)b * TT + q0) * EE + h * HD;
#pragma unroll
    for (int db = 0; db < 4; ++db)
#pragma unroll
        for (int r = 0; r < 4; ++r)
            op[(size_t)(4 * g + r) * EE + db * 16 + c] = o[db][r] * invl[r];
}

// ---------------------------------------------------------------------------
// Proj GEMM: out[8192,768] = attn[8192,768] @ Wproj[768,768] (f32)
// ---------------------------------------------------------------------------
__global__ __launch_bounds__(256)
void proj_gemm_kernel(const float* __restrict__ a, const float* __restrict__ w,
                      float* __restrict__ out) {
    __shared__ float As[64][17];
    __shared__ float Bs[16][68];
    const int bx = blockIdx.x;
    const int by = blockIdx.y;
    const int tid = threadIdx.x;
    const int tr = tid >> 4;
    const int tc = tid & 15;

    const int arow = tid >> 2;
    const int acol = (tid & 3) << 2;
    const int brow = tid >> 4;
    const int bcol = (tid & 15) << 2;

    const float* arow_p = a + (size_t)(by * 64 + arow) * EE;
    const float* wcol_p = w + (size_t)bx * 64;

    float acc[4][4] = {};

    for (int kt = 0; kt < EE / 16; ++kt) {
        float4 a4 = *(const float4*)(arow_p + kt * 16 + acol);
        float4 b4 = *(const float4*)(wcol_p + (size_t)(kt * 16 + brow) * EE + bcol);
        __syncthreads();
        As[arow][acol + 0] = a4.x; As[arow][acol + 1] = a4.y;
        As[arow][acol + 2] = a4.z; As[arow][acol + 3] = a4.w;
        Bs[brow][bcol + 0] = b4.x; Bs[brow][bcol + 1] = b4.y;
        Bs[brow][bcol + 2] = b4.z; Bs[brow][bcol + 3] = b4.w;
        __syncthreads();
#pragma unroll
        for (int kk = 0; kk < 16; ++kk) {
            float a_[4], b_[4];
#pragma unroll
            for (int i = 0; i < 4; ++i) a_[i] = As[tr * 4 + i][kk];
#pragma unroll
            for (int j = 0; j < 4; ++j) b_[j] = Bs[kk][tc * 4 + j];
#pragma unroll
            for (int i = 0; i < 4; ++i)
#pragma unroll
                for (int j = 0; j < 4; ++j) acc[i][j] += a_[i] * b_[j];
        }
    }

#pragma unroll
    for (int i = 0; i < 4; ++i) {
        const int mrow = by * 64 + tr * 4 + i;
        *(float4*)&out[(size_t)mrow * EE + bx * 64 + tc * 4] =
            make_float4(acc[i][0], acc[i][1], acc[i][2], acc[i][3]);
    }
}

extern "C" void kernel_launch(void* const* d_in, const int* in_sizes, int n_in,
                              void* d_out, int out_size, void* d_ws, size_t ws_size,
                              hipStream_t stream) {
    const float* x     = (const float*)d_in[0];
    const float* wqkv  = (const float*)d_in[1];
    const float* wproj = (const float*)d_in[2];
    float* out = (float*)d_out;

    unsigned short* q_ws = (unsigned short*)d_ws;                 // [B,H,T,64] bf16
    unsigned short* k_ws = q_ws + (size_t)BTE;                    // [B,H,T,64] bf16
    unsigned short* v_ws = q_ws + 2 * (size_t)BTE;                // [B,H,64,T] bf16
    float* attn_ws = (float*)((char*)d_ws + 3 * (size_t)BTE * 2); // [B,T,E] f32

    qkv_gemm_kernel<<<dim3(NQKV / 64, (BB * TT) / 64), 256, 0, stream>>>(x, wqkv, q_ws, k_ws, v_ws);
    attn_kernel<<<dim3(TT / 64, HH, BB), 256, 0, stream>>>(q_ws, k_ws, v_ws, attn_ws);
    proj_gemm_kernel<<<dim3(EE / 64, (BB * TT) / 64), 256, 0, stream>>>(attn_ws, wproj, out);
}

// Round 3
// 297.218 us; speedup vs baseline: 8.5687x; 2.5787x over previous
//
#include <hip/hip_runtime.h>
#include <hip/hip_bf16.h>

// B=4, T=2048, E=768, H=12, hd=64.
// Round 3: bf16 MFMA everywhere.
//   p1: xb = bf16(x)                      [8192][768]
//   p2: wqkv_t = bf16(Wqkv^T)             [2304][768]
//   p3: wproj_t = bf16(Wproj^T)           [768][768]
//   k1: qkv MFMA GEMM -> bf16 q,k [B,H,T,64], v^T [B,H,64,T]
//   k2: MFMA flash attention -> bf16 [B,T,E]
//   k3: proj MFMA GEMM -> f32 out

#define BB 4
#define TT 2048
#define EE 768
#define HH 12
#define HD 64
#define KK 768
#define BTE (BB*TT*EE)  // 6291456

typedef __attribute__((ext_vector_type(8))) short bf16x8;
typedef __attribute__((ext_vector_type(4))) float f32x4;

static __device__ __forceinline__ unsigned short f2bf(float f) {
    unsigned u = __builtin_bit_cast(unsigned, f);
    u += 0x7fffu + ((u >> 16) & 1u);   // RNE
    return (unsigned short)(u >> 16);
}

// ---------------------------------------------------------------------------
// x f32 -> bf16, 8 elems/thread
// ---------------------------------------------------------------------------
__global__ __launch_bounds__(256)
void convx_kernel(const float* __restrict__ x, unsigned short* __restrict__ xb) {
    const size_t i = ((size_t)blockIdx.x * 256 + threadIdx.x) * 8;
    float4 a = *(const float4*)&x[i];
    float4 b = *(const float4*)&x[i + 4];
    ushort4 lo, hi;
    lo.x = f2bf(a.x); lo.y = f2bf(a.y); lo.z = f2bf(a.z); lo.w = f2bf(a.w);
    hi.x = f2bf(b.x); hi.y = f2bf(b.y); hi.z = f2bf(b.z); hi.w = f2bf(b.w);
    *(ushort4*)&xb[i] = lo;
    *(ushort4*)&xb[i + 4] = hi;
}

// ---------------------------------------------------------------------------
// W[768][N] f32 -> Wt[N][768] bf16 (64x64 tiles via LDS)
// ---------------------------------------------------------------------------
__global__ __launch_bounds__(256)
void transw_kernel(const float* __restrict__ W, unsigned short* __restrict__ Wt, int N) {
    __shared__ unsigned short Ts[64][72];
    const int n0 = blockIdx.x * 64;
    const int k0 = blockIdx.y * 64;
    const int tid = threadIdx.x;
    {
        const int r = tid >> 4;
        const int c4 = (tid & 15) << 2;
#pragma unroll
        for (int i = 0; i < 4; ++i) {
            const int k = r + i * 16;
            float4 w4 = *(const float4*)&W[(size_t)(k0 + k) * N + n0 + c4];
            Ts[k][c4 + 0] = f2bf(w4.x); Ts[k][c4 + 1] = f2bf(w4.y);
            Ts[k][c4 + 2] = f2bf(w4.z); Ts[k][c4 + 3] = f2bf(w4.w);
        }
    }
    __syncthreads();
#pragma unroll
    for (int i = 0; i < 2; ++i) {
        const int idx = tid + i * 256;
        const int n = idx >> 3;
        const int ch = idx & 7;
        ushort4 p0, p1;
        p0.x = Ts[ch * 8 + 0][n]; p0.y = Ts[ch * 8 + 1][n];
        p0.z = Ts[ch * 8 + 2][n]; p0.w = Ts[ch * 8 + 3][n];
        p1.x = Ts[ch * 8 + 4][n]; p1.y = Ts[ch * 8 + 5][n];
        p1.z = Ts[ch * 8 + 6][n]; p1.w = Ts[ch * 8 + 7][n];
        *(ushort4*)&Wt[(size_t)(n0 + n) * KK + k0 + ch * 8] = p0;
        *(ushort4*)&Wt[(size_t)(n0 + n) * KK + k0 + ch * 8 + 4] = p1;
    }
}

// ---------------------------------------------------------------------------
// bf16 MFMA GEMM: C[M][N] = A[M][768] @ Wt[N][768]^T
// 128x128 tile, BK=32, 256 thr = 4 waves (2x2), acc 4x4 frags of 16x16x32.
// MODE 0: qkv scatter epilogue. MODE 1: f32 row-major out.
// ---------------------------------------------------------------------------
template<int MODE>
__global__ __launch_bounds__(256)
void mfma_gemm_kernel(const unsigned short* __restrict__ A,
                      const unsigned short* __restrict__ Wt,
                      unsigned short* __restrict__ q_ws,
                      unsigned short* __restrict__ k_ws,
                      unsigned short* __restrict__ v_ws,
                      float* __restrict__ outf) {
    __shared__ __align__(16) unsigned short As[128 * 40];   // pad: 80 B rows
    __shared__ __align__(16) unsigned short Bs[128 * 40];
    const int bx = blockIdx.x;
    const int by = blockIdx.y;
    const int tid = threadIdx.x;
    const int w = tid >> 6, lane = tid & 63;
    const int c = lane & 15, g = lane >> 4;
    const int wr = w >> 1, wc = w & 1;
    const int m0 = by * 128, n0 = bx * 128;

    const int r0 = tid >> 2;       // 0..63
    const int ch = tid & 3;        // 8-elem chunk

    const unsigned short* Ap = A  + (size_t)m0 * KK;
    const unsigned short* Bp = Wt + (size_t)n0 * KK;

    f32x4 acc[4][4] = {};

    for (int kt = 0; kt < KK / 32; ++kt) {
        const int k0 = kt * 32;
        const uint4 a0 = *(const uint4*)&Ap[(size_t)r0 * KK + k0 + ch * 8];
        const uint4 a1 = *(const uint4*)&Ap[(size_t)(r0 + 64) * KK + k0 + ch * 8];
        const uint4 b0 = *(const uint4*)&Bp[(size_t)r0 * KK + k0 + ch * 8];
        const uint4 b1 = *(const uint4*)&Bp[(size_t)(r0 + 64) * KK + k0 + ch * 8];
        __syncthreads();
        *(uint4*)&As[r0 * 40 + ch * 8]        = a0;
        *(uint4*)&As[(r0 + 64) * 40 + ch * 8] = a1;
        *(uint4*)&Bs[r0 * 40 + ch * 8]        = b0;
        *(uint4*)&Bs[(r0 + 64) * 40 + ch * 8] = b1;
        __syncthreads();

        bf16x8 af[4], bfr[4];
#pragma unroll
        for (int m = 0; m < 4; ++m)
            af[m] = *(const bf16x8*)&As[(wr * 64 + m * 16 + c) * 40 + g * 8];
#pragma unroll
        for (int n = 0; n < 4; ++n)
            bfr[n] = *(const bf16x8*)&Bs[(wc * 64 + n * 16 + c) * 40 + g * 8];
#pragma unroll
        for (int m = 0; m < 4; ++m)
#pragma unroll
            for (int n = 0; n < 4; ++n)
                acc[m][n] = __builtin_amdgcn_mfma_f32_16x16x32_bf16(af[m], bfr[n], acc[m][n], 0, 0, 0);
    }

    if (MODE == 0) {
        // n = n0 + wc*64 + n16*16 + c ; which = n0/768 (tiles don't cross)
        const int which = n0 / EE;
        const int h = (n0 % EE) / HD + wc;
        const int b = m0 / TT;                   // tiles don't cross batch
        const int tb = (m0 % TT) + wr * 64;
        if (which < 2) {
            unsigned short* dst = (which == 0) ? q_ws : k_ws;
            unsigned short* base = dst + (((size_t)b * HH + h) * TT) * HD;
#pragma unroll
            for (int m = 0; m < 4; ++m)
#pragma unroll
                for (int n = 0; n < 4; ++n)
#pragma unroll
                    for (int j = 0; j < 4; ++j)
                        base[(size_t)(tb + m * 16 + 4 * g + j) * HD + n * 16 + c] =
                            f2bf(acc[m][n][j]);
        } else {
            unsigned short* base = v_ws + (((size_t)b * HH + h) * HD) * TT;
#pragma unroll
            for (int m = 0; m < 4; ++m)
#pragma unroll
                for (int n = 0; n < 4; ++n)
#pragma unroll
                    for (int j = 0; j < 4; ++j)
                        base[(size_t)(n * 16 + c) * TT + tb + m * 16 + 4 * g + j] =
                            f2bf(acc[m][n][j]);
        }
    } else {
#pragma unroll
        for (int m = 0; m < 4; ++m)
#pragma unroll
            for (int n = 0; n < 4; ++n)
#pragma unroll
                for (int j = 0; j < 4; ++j)
                    outf[(size_t)(m0 + wr * 64 + m * 16 + 4 * g + j) * EE
                         + n0 + wc * 64 + n * 16 + c] = acc[m][n][j];
    }
}

// ---------------------------------------------------------------------------
// MFMA flash attention (as round 2), epilogue now bf16.
// ---------------------------------------------------------------------------
__global__ __launch_bounds__(256)
void attn_kernel(const unsigned short* __restrict__ q,
                 const unsigned short* __restrict__ k,
                 const unsigned short* __restrict__ vt,
                 unsigned short* __restrict__ attn_b) {
    __shared__ __align__(16) unsigned short Ks[64 * 72];
    __shared__ __align__(16) unsigned short Vt[64 * 72];
    __shared__ __align__(16) unsigned short Pb[4 * 16 * 72];

    const int qi = (TT / 64 - 1) - blockIdx.x;
    const int h = blockIdx.y, b = blockIdx.z;
    const int tid = threadIdx.x;
    const int w = tid >> 6;
    const int lane = tid & 63;
    const int c = lane & 15;
    const int g = lane >> 4;

    const size_t head_off = (size_t)(b * HH + h) * TT * HD;
    const unsigned short* qp = q + head_off;
    const unsigned short* kp = k + head_off;
    const unsigned short* vp = vt + head_off;

    const int q0 = qi * 64 + w * 16;

    const bf16x8 qa0 = *(const bf16x8*)&qp[(size_t)(q0 + c) * HD + g * 8];
    const bf16x8 qa1 = *(const bf16x8*)&qp[(size_t)(q0 + c) * HD + 32 + g * 8];

    f32x4 o[4] = {};
    float m_r[4], l_r[4];
#pragma unroll
    for (int r = 0; r < 4; ++r) { m_r[r] = -INFINITY; l_r[r] = 0.f; }

    const int skey = tid >> 2;
    const int sc = tid & 3;

    const int ktiles = qi + 1;
    for (int kt = 0; kt < ktiles; ++kt) {
        const int kv0 = kt * 64;
        const uint4 kA = *(const uint4*)&kp[(size_t)(kv0 + skey) * HD + sc * 16];
        const uint4 kB = *(const uint4*)&kp[(size_t)(kv0 + skey) * HD + sc * 16 + 8];
        const uint4 vA = *(const uint4*)&vp[(size_t)skey * TT + kv0 + sc * 16];
        const uint4 vB = *(const uint4*)&vp[(size_t)skey * TT + kv0 + sc * 16 + 8];
        __syncthreads();
        *(uint4*)&Ks[skey * 72 + sc * 16]     = kA;
        *(uint4*)&Ks[skey * 72 + sc * 16 + 8] = kB;
        *(uint4*)&Vt[skey * 72 + sc * 16]     = vA;
        *(uint4*)&Vt[skey * 72 + sc * 16 + 8] = vB;
        __syncthreads();

        f32x4 s[4];
#pragma unroll
        for (int kb = 0; kb < 4; ++kb) {
            const bf16x8 kb0 = *(const bf16x8*)&Ks[(kb * 16 + c) * 72 + g * 8];
            const bf16x8 kb1 = *(const bf16x8*)&Ks[(kb * 16 + c) * 72 + 32 + g * 8];
            f32x4 z = {0.f, 0.f, 0.f, 0.f};
            z = __builtin_amdgcn_mfma_f32_16x16x32_bf16(qa0, kb0, z, 0, 0, 0);
            s[kb] = __builtin_amdgcn_mfma_f32_16x16x32_bf16(qa1, kb1, z, 0, 0, 0);
        }

        float mx[4] = {-INFINITY, -INFINITY, -INFINITY, -INFINITY};
        if (kt == qi) {
#pragma unroll
            for (int kb = 0; kb < 4; ++kb)
#pragma unroll
                for (int r = 0; r < 4; ++r) {
                    const bool masked = (kv0 + kb * 16 + c) > (q0 + 4 * g + r);
                    s[kb][r] = masked ? -INFINITY : s[kb][r] * 0.125f;
                }
        } else {
#pragma unroll
            for (int kb = 0; kb < 4; ++kb)
#pragma unroll
                for (int r = 0; r < 4; ++r) s[kb][r] *= 0.125f;
        }
#pragma unroll
        for (int kb = 0; kb < 4; ++kb)
#pragma unroll
            for (int r = 0; r < 4; ++r) mx[r] = fmaxf(mx[r], s[kb][r]);
#pragma unroll
        for (int d = 1; d < 16; d <<= 1)
#pragma unroll
            for (int r = 0; r < 4; ++r) mx[r] = fmaxf(mx[r], __shfl_xor(mx[r], d));

        float al[4], ps[4];
#pragma unroll
        for (int r = 0; r < 4; ++r) {
            const float mn = fmaxf(m_r[r], mx[r]);
            al[r] = __expf(m_r[r] - mn);
            m_r[r] = mn;
            ps[r] = 0.f;
        }
#pragma unroll
        for (int kb = 0; kb < 4; ++kb)
#pragma unroll
            for (int r = 0; r < 4; ++r) {
                const float pv = __expf(s[kb][r] - m_r[r]);
                ps[r] += pv;
                Pb[w * 16 * 72 + (4 * g + r) * 72 + kb * 16 + c] = f2bf(pv);
            }
#pragma unroll
        for (int d = 1; d < 16; d <<= 1)
#pragma unroll
            for (int r = 0; r < 4; ++r) ps[r] += __shfl_xor(ps[r], d);
#pragma unroll
        for (int r = 0; r < 4; ++r) l_r[r] = l_r[r] * al[r] + ps[r];
#pragma unroll
        for (int db = 0; db < 4; ++db)
#pragma unroll
            for (int r = 0; r < 4; ++r) o[db][r] *= al[r];

        const bf16x8 pa0 = *(const bf16x8*)&Pb[w * 16 * 72 + c * 72 + g * 8];
        const bf16x8 pa1 = *(const bf16x8*)&Pb[w * 16 * 72 + c * 72 + 32 + g * 8];
#pragma unroll
        for (int db = 0; db < 4; ++db) {
            const bf16x8 vb0 = *(const bf16x8*)&Vt[(db * 16 + c) * 72 + g * 8];
            const bf16x8 vb1 = *(const bf16x8*)&Vt[(db * 16 + c) * 72 + 32 + g * 8];
            o[db] = __builtin_amdgcn_mfma_f32_16x16x32_bf16(pa0, vb0, o[db], 0, 0, 0);
            o[db] = __builtin_amdgcn_mfma_f32_16x16x32_bf16(pa1, vb1, o[db], 0, 0, 0);
        }
    }

    float invl[4];
#pragma unroll
    for (int r = 0; r < 4; ++r) invl[r] = 1.f / l_r[r];
    unsigned short* op = attn_b + ((size_t)b * TT + q0) * EE + h * HD;
#pragma unroll
    for (int db = 0; db < 4; ++db)
#pragma unroll
        for (int r = 0; r < 4; ++r)
            op[(size_t)(4 * g + r) * EE + db * 16 + c] = f2bf(o[db][r] * invl[r]);
}

extern "C" void kernel_launch(void* const* d_in, const int* in_sizes, int n_in,
                              void* d_out, int out_size, void* d_ws, size_t ws_size,
                              hipStream_t stream) {
    const float* x     = (const float*)d_in[0];
    const float* wqkv  = (const float*)d_in[1];
    const float* wproj = (const float*)d_in[2];
    float* out = (float*)d_out;

    unsigned short* ws = (unsigned short*)d_ws;
    unsigned short* q_ws    = ws;                    // [B,H,T,64]
    unsigned short* k_ws    = ws + (size_t)BTE;
    unsigned short* v_ws    = ws + 2 * (size_t)BTE;  // [B,H,64,T]
    unsigned short* xb      = ws + 3 * (size_t)BTE;  // [8192][768]
    unsigned short* attn_b  = ws + 4 * (size_t)BTE;  // [8192][768]
    unsigned short* wqkv_t  = ws + 5 * (size_t)BTE;  // [2304][768]
    unsigned short* wproj_t = wqkv_t + (size_t)2304 * 768;

    convx_kernel<<<BTE / 2048, 256, 0, stream>>>(x, xb);
    transw_kernel<<<dim3(2304 / 64, KK / 64), 256, 0, stream>>>(wqkv, wqkv_t, 2304);
    transw_kernel<<<dim3(768 / 64, KK / 64), 256, 0, stream>>>(wproj, wproj_t, 768);

    mfma_gemm_kernel<0><<<dim3(2304 / 128, 8192 / 128), 256, 0, stream>>>(
        xb, wqkv_t, q_ws, k_ws, v_ws, nullptr);
    attn_kernel<<<dim3(TT / 64, HH, BB), 256, 0, stream>>>(q_ws, k_ws, v_ws, attn_b);
    mfma_gemm_kernel<1><<<dim3(EE / 128, 8192 / 128), 256, 0, stream>>>(
        attn_b, wproj_t, nullptr, nullptr, nullptr, out);
}